// Round 6
// baseline (843.849 us; speedup 1.0000x reference)
//
#include <hip/hip_runtime.h>
#include <cstdint>
#include <cmath>

#define SS 2048
#define HH 1024

typedef __bf16 bf16_t;
typedef __bf16 bf16x8 __attribute__((ext_vector_type(8)));
typedef __bf16 bf16x4 __attribute__((ext_vector_type(4)));
typedef float  f32x4  __attribute__((ext_vector_type(4)));

union U32P { unsigned u; bf16_t h[2]; };

__device__ __forceinline__ void async_load16(const void* g, void* l) {
  __builtin_amdgcn_global_load_lds(
      (__attribute__((address_space(1))) void*)(g),
      (__attribute__((address_space(3))) void*)(l), 16, 0, 0);
}

// ---------------- fp32 -> bf16 convert ------------------------------------
__global__ __launch_bounds__(256) void cvt_kernel(const float* __restrict__ in,
                                                  bf16_t* __restrict__ out) {
  size_t i = (size_t)blockIdx.x * 256 + threadIdx.x;
  f32x4 v = ((const f32x4*)in)[i];
  bf16x4 o;
  o[0] = (bf16_t)v[0]; o[1] = (bf16_t)v[1]; o[2] = (bf16_t)v[2]; o[3] = (bf16_t)v[3];
  ((bf16x4*)out)[i] = o;
}

// ---------------- LayerNorm: fp32 in [4096,1024] -> bf16 out ---------------
__global__ __launch_bounds__(256) void ln_kernel(const float* __restrict__ x,
                                                 const float* __restrict__ w,
                                                 const float* __restrict__ b,
                                                 bf16_t* __restrict__ out) {
  const int row = blockIdx.x;
  const int tid = threadIdx.x;
  const f32x4 v = ((const f32x4*)(x + (size_t)row * HH))[tid];
  float s  = v[0] + v[1] + v[2] + v[3];
  float s2 = v[0]*v[0] + v[1]*v[1] + v[2]*v[2] + v[3]*v[3];
#pragma unroll
  for (int o = 1; o < 64; o <<= 1) { s += __shfl_xor(s, o); s2 += __shfl_xor(s2, o); }
  __shared__ float r1[4], r2[4];
  if ((tid & 63) == 0) { r1[tid >> 6] = s; r2[tid >> 6] = s2; }
  __syncthreads();
  float ts  = r1[0] + r1[1] + r1[2] + r1[3];
  float ts2 = r2[0] + r2[1] + r2[2] + r2[3];
  float mu  = ts * (1.0f / HH);
  float var = ts2 * (1.0f / HH) - mu * mu;
  float rstd = rsqrtf(var + 1e-5f);
  f32x4 wv = ((const f32x4*)w)[tid];
  f32x4 bv = ((const f32x4*)b)[tid];
  bf16x4 o;
#pragma unroll
  for (int j = 0; j < 4; ++j) o[j] = (bf16_t)((v[j] - mu) * rstd * wv[j] + bv[j]);
  ((bf16x4*)(out + (size_t)row * HH))[tid] = o;
}

__device__ __forceinline__ float gelu_f(float x) {
  return 0.5f * x * (1.0f + erff(x * 0.70710678118654752f));
}

// ---- fused residual add: x += p0 + p1 + bias -------------------------------
__global__ __launch_bounds__(256) void fuse_add(float* __restrict__ x,
                                                const bf16_t* __restrict__ p0,
                                                const bf16_t* __restrict__ p1,
                                                const float* __restrict__ bias) {
  size_t i = (size_t)blockIdx.x * 256 + threadIdx.x;
  f32x4 xv = ((f32x4*)x)[i];
  bf16x4 a = ((const bf16x4*)p0)[i];
  bf16x4 b4 = ((const bf16x4*)p1)[i];
  f32x4 bv = ((const f32x4*)bias)[i & 255];
#pragma unroll
  for (int j = 0; j < 4; ++j) xv[j] += (float)a[j] + (float)b4[j] + bv[j];
  ((f32x4*)x)[i] = xv;
}

// ---------------- GEMM: C = A * W^T + bias; EPI 1=bias+gelu -----------------
template <int EPI>
__global__ __launch_bounds__(256) void gemm_bt(const bf16_t* __restrict__ A,
                                               const bf16_t* __restrict__ W,
                                               const float* __restrict__ bias,
                                               bf16_t* __restrict__ outb,
                                               int M, int N, int K) {
  __shared__ __align__(16) bf16_t As[128 * 64];
  __shared__ __align__(16) bf16_t Bs[128 * 64];
  const int tid = threadIdx.x;
  const int w = tid >> 6, lane = tid & 63;
  const int m16 = lane & 15, quad = lane >> 4;
  const int wm = w & 1, wn = w >> 1;
  const int n0 = blockIdx.x * 128, m0 = blockIdx.y * 128;

  f32x4 acc[4][4];
#pragma unroll
  for (int i = 0; i < 4; ++i)
#pragma unroll
    for (int j = 0; j < 4; ++j) acc[i][j] = (f32x4){0.f, 0.f, 0.f, 0.f};

  int rowi[4], gci[4];
#pragma unroll
  for (int i = 0; i < 4; ++i) {
    int p = (w * 4 + i) * 64 + lane;
    rowi[i] = p >> 3;
    gci[i] = ((lane & 7) ^ (rowi[i] & 7)) * 8;
  }

  for (int kt = 0; kt < K; kt += 64) {
    __syncthreads();
#pragma unroll
    for (int i = 0; i < 4; ++i) {
      async_load16(A + (size_t)(m0 + rowi[i]) * K + kt + gci[i], &As[(w * 4 + i) * 512]);
      async_load16(W + (size_t)(n0 + rowi[i]) * K + kt + gci[i], &Bs[(w * 4 + i) * 512]);
    }
    __syncthreads();
#pragma unroll
    for (int kk = 0; kk < 2; ++kk) {
      bf16x8 af[4], bfv[4];
#pragma unroll
      for (int mi = 0; mi < 4; ++mi) {
        int row = wm * 64 + mi * 16 + m16;
        int cpos = (kk * 4 + quad) ^ (row & 7);
        af[mi] = *(const bf16x8*)&As[row * 64 + cpos * 8];
      }
#pragma unroll
      for (int ni = 0; ni < 4; ++ni) {
        int row = wn * 64 + ni * 16 + m16;
        int cpos = (kk * 4 + quad) ^ (row & 7);
        bfv[ni] = *(const bf16x8*)&Bs[row * 64 + cpos * 8];
      }
#pragma unroll
      for (int mi = 0; mi < 4; ++mi)
#pragma unroll
        for (int ni = 0; ni < 4; ++ni)
          acc[mi][ni] = __builtin_amdgcn_mfma_f32_16x16x32_bf16(af[mi], bfv[ni],
                                                                acc[mi][ni], 0, 0, 0);
    }
  }

#pragma unroll
  for (int ni = 0; ni < 4; ++ni) {
    int col = n0 + wn * 64 + ni * 16 + m16;
    float bv = bias[col];
#pragma unroll
    for (int mi = 0; mi < 4; ++mi) {
      int rowb = m0 + wm * 64 + mi * 16 + quad * 4;
#pragma unroll
      for (int r = 0; r < 4; ++r) {
        size_t idx = (size_t)(rowb + r) * N + col;
        float v = acc[mi][ni][r] + bv;
        if constexpr (EPI == 1) v = gelu_f(v);
        outb[idx] = (bf16_t)v;
      }
    }
  }
}

// ---- QKV GEMM: M=4096,N=3072,K=1024. Q -> qq row-major; K -> kp[bh][t][d];
// ---- V -> vT[bh][d][t] (transposed; 4-token packs -> 8B stores). ----------
__global__ __launch_bounds__(256) void gemm_qkv(const bf16_t* __restrict__ A,
                                                const bf16_t* __restrict__ W,
                                                const float* __restrict__ bias,
                                                bf16_t* __restrict__ qq,
                                                bf16_t* __restrict__ kpb,
                                                bf16_t* __restrict__ vtb) {
  __shared__ __align__(16) bf16_t As[128 * 64];
  __shared__ __align__(16) bf16_t Bs[128 * 64];
  const int K = 1024;
  const int tid = threadIdx.x;
  const int w = tid >> 6, lane = tid & 63;
  const int m16 = lane & 15, quad = lane >> 4;
  const int wm = w & 1, wn = w >> 1;
  const int n0 = blockIdx.x * 128, m0 = blockIdx.y * 128;

  f32x4 acc[4][4];
#pragma unroll
  for (int i = 0; i < 4; ++i)
#pragma unroll
    for (int j = 0; j < 4; ++j) acc[i][j] = (f32x4){0.f, 0.f, 0.f, 0.f};

  int rowi[4], gci[4];
#pragma unroll
  for (int i = 0; i < 4; ++i) {
    int p = (w * 4 + i) * 64 + lane;
    rowi[i] = p >> 3;
    gci[i] = ((lane & 7) ^ (rowi[i] & 7)) * 8;
  }

  for (int kt = 0; kt < K; kt += 64) {
    __syncthreads();
#pragma unroll
    for (int i = 0; i < 4; ++i) {
      async_load16(A + (size_t)(m0 + rowi[i]) * K + kt + gci[i], &As[(w * 4 + i) * 512]);
      async_load16(W + (size_t)(n0 + rowi[i]) * K + kt + gci[i], &Bs[(w * 4 + i) * 512]);
    }
    __syncthreads();
#pragma unroll
    for (int kk = 0; kk < 2; ++kk) {
      bf16x8 af[4], bfv[4];
#pragma unroll
      for (int mi = 0; mi < 4; ++mi) {
        int row = wm * 64 + mi * 16 + m16;
        int cpos = (kk * 4 + quad) ^ (row & 7);
        af[mi] = *(const bf16x8*)&As[row * 64 + cpos * 8];
      }
#pragma unroll
      for (int ni = 0; ni < 4; ++ni) {
        int row = wn * 64 + ni * 16 + m16;
        int cpos = (kk * 4 + quad) ^ (row & 7);
        bfv[ni] = *(const bf16x8*)&Bs[row * 64 + cpos * 8];
      }
#pragma unroll
      for (int mi = 0; mi < 4; ++mi)
#pragma unroll
        for (int ni = 0; ni < 4; ++ni)
          acc[mi][ni] = __builtin_amdgcn_mfma_f32_16x16x32_bf16(af[mi], bfv[ni],
                                                                acc[mi][ni], 0, 0, 0);
    }
  }

  const int sec = n0 >> 10;  // 0=Q, 1=K, 2=V (block-uniform: n0 is 128-aligned)
#pragma unroll
  for (int ni = 0; ni < 4; ++ni) {
    int col = n0 + wn * 64 + ni * 16 + m16;
    float bv = bias[col];
    int c2 = col & 1023, hh = c2 >> 6, d = c2 & 63;
#pragma unroll
    for (int mi = 0; mi < 4; ++mi) {
      int rowb = m0 + wm * 64 + mi * 16 + quad * 4;
      int bb = rowb >> 11, t = rowb & 2047;
      float v[4];
#pragma unroll
      for (int r = 0; r < 4; ++r) v[r] = acc[mi][ni][r] + bv;
      if (sec == 0) {
#pragma unroll
        for (int r = 0; r < 4; ++r)
          qq[(size_t)(rowb + r) * 1024 + col] = (bf16_t)v[r];
      } else if (sec == 1) {
        bf16_t* kdst = kpb + (((size_t)(bb * 16 + hh) * 2048 + t) * 64 + d);
#pragma unroll
        for (int r = 0; r < 4; ++r) kdst[r * 64] = (bf16_t)v[r];
      } else {
        U32P a2, c3;
        a2.h[0] = (bf16_t)v[0]; a2.h[1] = (bf16_t)v[1];
        c3.h[0] = (bf16_t)v[2]; c3.h[1] = (bf16_t)v[3];
        uint2 pk; pk.x = a2.u; pk.y = c3.u;
        *(uint2*)(vtb + (((size_t)(bb * 16 + hh) * 64 + d) * 2048 + t)) = pk;
      }
    }
  }
}

// ---- split-K=2 GEMM -> bf16 partial buffers (no bias) ----------------------
__global__ __launch_bounds__(256) void gemm_sk2(const bf16_t* __restrict__ A,
                                                const bf16_t* __restrict__ W,
                                                bf16_t* __restrict__ p0,
                                                bf16_t* __restrict__ p1,
                                                int M, int N, int K) {
  __shared__ __align__(16) bf16_t As[128 * 64];
  __shared__ __align__(16) bf16_t Bs[128 * 64];
  const int tid = threadIdx.x;
  const int w = tid >> 6, lane = tid & 63;
  const int m16 = lane & 15, quad = lane >> 4;
  const int wm = w & 1, wn = w >> 1;
  const int n0 = blockIdx.x * 128, m0 = blockIdx.y * 128;
  const int z = blockIdx.z;
  const int kbeg = z * (K >> 1), kend = kbeg + (K >> 1);
  bf16_t* outb = z ? p1 : p0;

  f32x4 acc[4][4];
#pragma unroll
  for (int i = 0; i < 4; ++i)
#pragma unroll
    for (int j = 0; j < 4; ++j) acc[i][j] = (f32x4){0.f, 0.f, 0.f, 0.f};

  int rowi[4], gci[4];
#pragma unroll
  for (int i = 0; i < 4; ++i) {
    int p = (w * 4 + i) * 64 + lane;
    rowi[i] = p >> 3;
    gci[i] = ((lane & 7) ^ (rowi[i] & 7)) * 8;
  }

  for (int kt = kbeg; kt < kend; kt += 64) {
    __syncthreads();
#pragma unroll
    for (int i = 0; i < 4; ++i) {
      async_load16(A + (size_t)(m0 + rowi[i]) * K + kt + gci[i], &As[(w * 4 + i) * 512]);
      async_load16(W + (size_t)(n0 + rowi[i]) * K + kt + gci[i], &Bs[(w * 4 + i) * 512]);
    }
    __syncthreads();
#pragma unroll
    for (int kk = 0; kk < 2; ++kk) {
      bf16x8 af[4], bfv[4];
#pragma unroll
      for (int mi = 0; mi < 4; ++mi) {
        int row = wm * 64 + mi * 16 + m16;
        int cpos = (kk * 4 + quad) ^ (row & 7);
        af[mi] = *(const bf16x8*)&As[row * 64 + cpos * 8];
      }
#pragma unroll
      for (int ni = 0; ni < 4; ++ni) {
        int row = wn * 64 + ni * 16 + m16;
        int cpos = (kk * 4 + quad) ^ (row & 7);
        bfv[ni] = *(const bf16x8*)&Bs[row * 64 + cpos * 8];
      }
#pragma unroll
      for (int mi = 0; mi < 4; ++mi)
#pragma unroll
        for (int ni = 0; ni < 4; ++ni)
          acc[mi][ni] = __builtin_amdgcn_mfma_f32_16x16x32_bf16(af[mi], bfv[ni],
                                                                acc[mi][ni], 0, 0, 0);
    }
  }

#pragma unroll
  for (int ni = 0; ni < 4; ++ni) {
    int col = n0 + wn * 64 + ni * 16 + m16;
#pragma unroll
    for (int mi = 0; mi < 4; ++mi) {
      int rowb = m0 + wm * 64 + mi * 16 + quad * 4;
#pragma unroll
      for (int r = 0; r < 4; ++r) {
        size_t idx = (size_t)(rowb + r) * N + col;
        outb[idx] = (bf16_t)acc[mi][ni][r];
      }
    }
  }
}

// ---------------- Flash attention v6: per-wave, no LDS, no barriers ---------
// One wave per (bh, 16-query strip). Keys stepped 32/iter. S-MFMA uses an
// INTERLEAVED key-row order (step X: keys quad*8+r, step Y: quad*8+4+r) so
// the S output registers are byte-exactly the PV B-operand fragment (k =
// quad*8+j) -> P never leaves registers. V is read transposed (vT) as the
// PV A-operand: one 16B load per 16-d segment. Stateless log2-softmax with
// analytic max; causal mask == (alibi offset > 0). ALiBi window pruning.
__global__ __launch_bounds__(256, 4) void attn_kernel(const bf16_t* __restrict__ qq,
                                                      const bf16_t* __restrict__ kp,
                                                      const bf16_t* __restrict__ vT,
                                                      bf16_t* __restrict__ ctx) {
  const int u = blockIdx.x * 4 + (threadIdx.x >> 6);
  const int bh = u & 31;
  const int q16 = 127 - (u >> 5);  // heavy strips first
  const int b = bh >> 4, h = bh & 15;
  const int lane = threadIdx.x & 63;
  const int m16 = lane & 15, quad = lane >> 4;
  const int q_lo = q16 << 4, q_hi = q_lo + 15;

  const float slope2 = __builtin_amdgcn_exp2f(-0.5f * (float)(h + 1))
                       * 1.4426950408889634f;  // slope_h * log2(e)
  int k_min = q_lo - (int)(30.0f / slope2);
  k_min = (k_min < 0) ? 0 : (k_min & ~31);

  // Q B-fragments (n=q, k=d)
  const bf16_t* qb = qq + (size_t)(b * SS + q_lo + m16) * 1024 + h * 64 + quad * 8;
  const bf16x8 bq0 = *(const bf16x8*)(qb);
  const bf16x8 bq1 = *(const bf16x8*)(qb + 32);

  // K A-row interleave: step X key(m16) = (m16>>3... rX maps m -> quad(m)*8 + r(m)
  const int rX = ((m16 >> 2) << 3) + (m16 & 3);
  const bf16_t* kb0 = kp + ((size_t)bh * 2048 + rX) * 64 + quad * 8;
  const bf16_t* vb0 = vT + ((size_t)bh * 64 + m16) * 2048 + quad * 8;

  const float d32 = slope2 * 32.0f;
  float alkX[4], alkY[4];
#pragma unroll
  for (int r = 0; r < 4; ++r) {
    alkX[r] = slope2 * (float)(k_min + quad * 8 + r - q_lo - m16);
    alkY[r] = alkX[r] + slope2 * 4.0f;
  }

  f32x4 acc[4];
#pragma unroll
  for (int i = 0; i < 4; ++i) acc[i] = (f32x4){0.f, 0.f, 0.f, 0.f};
  float rs = 0.f;
  constexpr float C = 0.18033688011112042f;  // log2(e)/8

  // preload K for first iteration (V loaded in-iteration)
  bf16x8 aX0, aX1, aY0, aY1;
  {
    const bf16_t* kx = kb0 + (size_t)k_min * 64;
    aX0 = *(const bf16x8*)(kx);
    aX1 = *(const bf16x8*)(kx + 32);
    aY0 = *(const bf16x8*)(kx + 256);   // +4 key rows
    aY1 = *(const bf16x8*)(kx + 288);
  }

  for (int kb = k_min; kb <= q_hi; kb += 32) {
    // V fragments for this iteration (consumed after softmax -> partial hide)
    const bf16_t* vx = vb0 + kb;
    bf16x8 av0 = *(const bf16x8*)(vx);
    bf16x8 av1 = *(const bf16x8*)(vx + 16 * 2048);
    bf16x8 av2 = *(const bf16x8*)(vx + 32 * 2048);
    bf16x8 av3 = *(const bf16x8*)(vx + 48 * 2048);
    // prefetch next K
    bf16x8 nX0 = aX0, nX1 = aX1, nY0 = aY0, nY1 = aY1;
    if (kb + 32 <= q_hi) {
      const bf16_t* kx = kb0 + (size_t)(kb + 32) * 64;
      nX0 = *(const bf16x8*)(kx);
      nX1 = *(const bf16x8*)(kx + 32);
      nY0 = *(const bf16x8*)(kx + 256);
      nY1 = *(const bf16x8*)(kx + 288);
    }

    f32x4 zX = (f32x4){0.f, 0.f, 0.f, 0.f};
    zX = __builtin_amdgcn_mfma_f32_16x16x32_bf16(aX0, bq0, zX, 0, 0, 0);
    zX = __builtin_amdgcn_mfma_f32_16x16x32_bf16(aX1, bq1, zX, 0, 0, 0);
    f32x4 zY = (f32x4){0.f, 0.f, 0.f, 0.f};
    zY = __builtin_amdgcn_mfma_f32_16x16x32_bf16(aY0, bq0, zY, 0, 0, 0);
    zY = __builtin_amdgcn_mfma_f32_16x16x32_bf16(aY1, bq1, zY, 0, 0, 0);

    bf16x8 bp;
#pragma unroll
    for (int r = 0; r < 4; ++r) {
      float sX = fmaf(zX[r], C, alkX[r]);
      float sY = fmaf(zY[r], C, alkY[r]);
      float eX = (alkX[r] > 0.0f) ? 0.0f : __builtin_amdgcn_exp2f(sX);
      float eY = (alkY[r] > 0.0f) ? 0.0f : __builtin_amdgcn_exp2f(sY);
      bp[r] = (bf16_t)eX;
      bp[4 + r] = (bf16_t)eY;
      rs += eX + eY;
      alkX[r] += d32;
      alkY[r] += d32;
    }

    acc[0] = __builtin_amdgcn_mfma_f32_16x16x32_bf16(av0, bp, acc[0], 0, 0, 0);
    acc[1] = __builtin_amdgcn_mfma_f32_16x16x32_bf16(av1, bp, acc[1], 0, 0, 0);
    acc[2] = __builtin_amdgcn_mfma_f32_16x16x32_bf16(av2, bp, acc[2], 0, 0, 0);
    acc[3] = __builtin_amdgcn_mfma_f32_16x16x32_bf16(av3, bp, acc[3], 0, 0, 0);

    aX0 = nX0; aX1 = nX1; aY0 = nY0; aY1 = nY1;
  }

  // l: sum across quads (lanes with same q=m16)
  rs += __shfl_xor(rs, 16);
  rs += __shfl_xor(rs, 32);
  const float inv = 1.0f / rs;
  // lane holds O^T[d = seg*16 + quad*4 + r][q = q_lo + m16]
  bf16_t* cb = ctx + (size_t)(b * SS + q_lo + m16) * 1024 + h * 64 + quad * 4;
#pragma unroll
  for (int s = 0; s < 4; ++s) {
    U32P a2, c2;
    a2.h[0] = (bf16_t)(acc[s][0] * inv); a2.h[1] = (bf16_t)(acc[s][1] * inv);
    c2.h[0] = (bf16_t)(acc[s][2] * inv); c2.h[1] = (bf16_t)(acc[s][3] * inv);
    uint2 pk; pk.x = a2.u; pk.y = c2.u;
    *(uint2*)(cb + s * 16) = pk;
  }
}

// ---------------------------------------------------------------------------
extern "C" void kernel_launch(void* const* d_in, const int* in_sizes, int n_in,
                              void* d_out, int out_size, void* d_ws, size_t ws_size,
                              hipStream_t stream) {
  const float* hs    = (const float*)d_in[0];
  const float* qkvw  = (const float*)d_in[2];
  const float* qkvb  = (const float*)d_in[3];
  const float* dw    = (const float*)d_in[4];
  const float* db    = (const float*)d_in[5];
  const float* w1    = (const float*)d_in[6];
  const float* b1    = (const float*)d_in[7];
  const float* w2    = (const float*)d_in[8];
  const float* b2    = (const float*)d_in[9];
  const float* ln1w  = (const float*)d_in[10];
  const float* ln1b  = (const float*)d_in[11];
  const float* ln2w  = (const float*)d_in[12];
  const float* ln2b  = (const float*)d_in[13];
  float* x = (float*)d_out;  // residual stream, fp32 [4096,1024]

  char* ws = (char*)d_ws;
  bf16_t* wq  = (bf16_t*)(ws + 0);         // 6 MB
  bf16_t* wd  = (bf16_t*)(ws + 6291456);   // 2 MB
  bf16_t* w1c = (bf16_t*)(ws + 8388608);   // 8 MB
  bf16_t* w2c = (bf16_t*)(ws + 16777216);  // 8 MB
  bf16_t* hb  = (bf16_t*)(ws + 25165824);  // 8 MB (ln out / mlp2 partial0)
  bf16_t* qq  = (bf16_t*)(ws + 33554432);  // 8 MB Q rows
  bf16_t* kpb = (bf16_t*)(ws + 41943040);  // 8 MB K packed [bh][t][d]
  bf16_t* vtb = (bf16_t*)(ws + 50331648);  // 8 MB V transposed [bh][d][t]
  bf16_t* cx  = (bf16_t*)(ws + 58720256);  // 8 MB attn ctx
  bf16_t* qmid = (bf16_t*)(ws + 33554432); // 32 MB mlp-mid (aliases qq/kp/vT/cx; all dead)
  bf16_t* p2b = (bf16_t*)(ws + 67108864);  // 8 MB mlp2 partial1
  bf16_t* dp0 = qq;                        // dense partials (qq/kp dead post-attn)
  bf16_t* dp1 = kpb;

  hipMemcpyAsync(x, hs, (size_t)4096 * 1024 * 4, hipMemcpyDeviceToDevice, stream);

  for (int l = 0; l < 2; ++l) {
    cvt_kernel<<<3072, 256, 0, stream>>>(qkvw + (size_t)l * 3145728, wq);
    cvt_kernel<<<1024, 256, 0, stream>>>(dw + (size_t)l * 1048576, wd);
    cvt_kernel<<<4096, 256, 0, stream>>>(w1 + (size_t)l * 4194304, w1c);
    cvt_kernel<<<4096, 256, 0, stream>>>(w2 + (size_t)l * 4194304, w2c);

    ln_kernel<<<4096, 256, 0, stream>>>(x, ln1w + l * 1024, ln1b + l * 1024, hb);
    gemm_qkv<<<dim3(24, 32), 256, 0, stream>>>(hb, wq, qkvb + l * 3072, qq, kpb, vtb);
    attn_kernel<<<1024, 256, 0, stream>>>(qq, kpb, vtb, cx);
    gemm_sk2<<<dim3(8, 32, 2), 256, 0, stream>>>(cx, wd, dp0, dp1, 4096, 1024, 1024);
    fuse_add<<<4096, 256, 0, stream>>>(x, dp0, dp1, db + l * 1024);
    ln_kernel<<<4096, 256, 0, stream>>>(x, ln2w + l * 1024, ln2b + l * 1024, hb);
    gemm_bt<1><<<dim3(32, 32), 256, 0, stream>>>(hb, w1c, b1 + l * 4096, qmid,
                                                 4096, 4096, 1024);
    gemm_sk2<<<dim3(8, 32, 2), 256, 0, stream>>>(qmid, w2c, hb, p2b, 4096, 1024, 4096);
    fuse_add<<<4096, 256, 0, stream>>>(x, hb, p2b, b2 + l * 1024);
  }
}

// Round 7
// 843.261 us; speedup vs baseline: 1.0007x; 1.0007x over previous
//
#include <hip/hip_runtime.h>
#include <cstdint>
#include <cmath>

#define SS 2048
#define HH 1024

typedef __bf16 bf16_t;
typedef __bf16 bf16x8 __attribute__((ext_vector_type(8)));
typedef __bf16 bf16x4 __attribute__((ext_vector_type(4)));
typedef float  f32x4  __attribute__((ext_vector_type(4)));

union U32P { unsigned u; bf16_t h[2]; };

__device__ __forceinline__ void async_load16(const void* g, void* l) {
  __builtin_amdgcn_global_load_lds(
      (__attribute__((address_space(1))) void*)(g),
      (__attribute__((address_space(3))) void*)(l), 16, 0, 0);
}

// ---------------- fp32 -> bf16 convert ------------------------------------
__global__ __launch_bounds__(256) void cvt_kernel(const float* __restrict__ in,
                                                  bf16_t* __restrict__ out) {
  size_t i = (size_t)blockIdx.x * 256 + threadIdx.x;
  f32x4 v = ((const f32x4*)in)[i];
  bf16x4 o;
  o[0] = (bf16_t)v[0]; o[1] = (bf16_t)v[1]; o[2] = (bf16_t)v[2]; o[3] = (bf16_t)v[3];
  ((bf16x4*)out)[i] = o;
}

// ---------------- LayerNorm: fp32 in [4096,1024] -> bf16 out ---------------
__global__ __launch_bounds__(256) void ln_kernel(const float* __restrict__ x,
                                                 const float* __restrict__ w,
                                                 const float* __restrict__ b,
                                                 bf16_t* __restrict__ out) {
  const int row = blockIdx.x;
  const int tid = threadIdx.x;
  const f32x4 v = ((const f32x4*)(x + (size_t)row * HH))[tid];
  float s  = v[0] + v[1] + v[2] + v[3];
  float s2 = v[0]*v[0] + v[1]*v[1] + v[2]*v[2] + v[3]*v[3];
#pragma unroll
  for (int o = 1; o < 64; o <<= 1) { s += __shfl_xor(s, o); s2 += __shfl_xor(s2, o); }
  __shared__ float r1[4], r2[4];
  if ((tid & 63) == 0) { r1[tid >> 6] = s; r2[tid >> 6] = s2; }
  __syncthreads();
  float ts  = r1[0] + r1[1] + r1[2] + r1[3];
  float ts2 = r2[0] + r2[1] + r2[2] + r2[3];
  float mu  = ts * (1.0f / HH);
  float var = ts2 * (1.0f / HH) - mu * mu;
  float rstd = rsqrtf(var + 1e-5f);
  f32x4 wv = ((const f32x4*)w)[tid];
  f32x4 bv = ((const f32x4*)b)[tid];
  bf16x4 o;
#pragma unroll
  for (int j = 0; j < 4; ++j) o[j] = (bf16_t)((v[j] - mu) * rstd * wv[j] + bv[j]);
  ((bf16x4*)(out + (size_t)row * HH))[tid] = o;
}

__device__ __forceinline__ float gelu_f(float x) {
  return 0.5f * x * (1.0f + erff(x * 0.70710678118654752f));
}

// ---- fused residual add: x += p0 + p1 + bias -------------------------------
__global__ __launch_bounds__(256) void fuse_add(float* __restrict__ x,
                                                const bf16_t* __restrict__ p0,
                                                const bf16_t* __restrict__ p1,
                                                const float* __restrict__ bias) {
  size_t i = (size_t)blockIdx.x * 256 + threadIdx.x;
  f32x4 xv = ((f32x4*)x)[i];
  bf16x4 a = ((const bf16x4*)p0)[i];
  bf16x4 b4 = ((const bf16x4*)p1)[i];
  f32x4 bv = ((const f32x4*)bias)[i & 255];
#pragma unroll
  for (int j = 0; j < 4; ++j) xv[j] += (float)a[j] + (float)b4[j] + bv[j];
  ((f32x4*)x)[i] = xv;
}

// ---------------- GEMM: C = A * W^T + bias; EPI 1=bias+gelu -----------------
template <int EPI>
__global__ __launch_bounds__(256) void gemm_bt(const bf16_t* __restrict__ A,
                                               const bf16_t* __restrict__ W,
                                               const float* __restrict__ bias,
                                               bf16_t* __restrict__ outb,
                                               int M, int N, int K) {
  __shared__ __align__(16) bf16_t As[128 * 64];
  __shared__ __align__(16) bf16_t Bs[128 * 64];
  const int tid = threadIdx.x;
  const int w = tid >> 6, lane = tid & 63;
  const int m16 = lane & 15, quad = lane >> 4;
  const int wm = w & 1, wn = w >> 1;
  const int n0 = blockIdx.x * 128, m0 = blockIdx.y * 128;

  f32x4 acc[4][4];
#pragma unroll
  for (int i = 0; i < 4; ++i)
#pragma unroll
    for (int j = 0; j < 4; ++j) acc[i][j] = (f32x4){0.f, 0.f, 0.f, 0.f};

  int rowi[4], gci[4];
#pragma unroll
  for (int i = 0; i < 4; ++i) {
    int p = (w * 4 + i) * 64 + lane;
    rowi[i] = p >> 3;
    gci[i] = ((lane & 7) ^ (rowi[i] & 7)) * 8;
  }

  for (int kt = 0; kt < K; kt += 64) {
    __syncthreads();
#pragma unroll
    for (int i = 0; i < 4; ++i) {
      async_load16(A + (size_t)(m0 + rowi[i]) * K + kt + gci[i], &As[(w * 4 + i) * 512]);
      async_load16(W + (size_t)(n0 + rowi[i]) * K + kt + gci[i], &Bs[(w * 4 + i) * 512]);
    }
    __syncthreads();
#pragma unroll
    for (int kk = 0; kk < 2; ++kk) {
      bf16x8 af[4], bfv[4];
#pragma unroll
      for (int mi = 0; mi < 4; ++mi) {
        int row = wm * 64 + mi * 16 + m16;
        int cpos = (kk * 4 + quad) ^ (row & 7);
        af[mi] = *(const bf16x8*)&As[row * 64 + cpos * 8];
      }
#pragma unroll
      for (int ni = 0; ni < 4; ++ni) {
        int row = wn * 64 + ni * 16 + m16;
        int cpos = (kk * 4 + quad) ^ (row & 7);
        bfv[ni] = *(const bf16x8*)&Bs[row * 64 + cpos * 8];
      }
#pragma unroll
      for (int mi = 0; mi < 4; ++mi)
#pragma unroll
        for (int ni = 0; ni < 4; ++ni)
          acc[mi][ni] = __builtin_amdgcn_mfma_f32_16x16x32_bf16(af[mi], bfv[ni],
                                                                acc[mi][ni], 0, 0, 0);
    }
  }

#pragma unroll
  for (int ni = 0; ni < 4; ++ni) {
    int col = n0 + wn * 64 + ni * 16 + m16;
    float bv = bias[col];
#pragma unroll
    for (int mi = 0; mi < 4; ++mi) {
      int rowb = m0 + wm * 64 + mi * 16 + quad * 4;
#pragma unroll
      for (int r = 0; r < 4; ++r) {
        size_t idx = (size_t)(rowb + r) * N + col;
        float v = acc[mi][ni][r] + bv;
        if constexpr (EPI == 1) v = gelu_f(v);
        outb[idx] = (bf16_t)v;
      }
    }
  }
}

// ---- QKV GEMM: Q -> qq row-major; K -> kp[bh][t][d]; V -> vT[bh][d][t] -----
__global__ __launch_bounds__(256) void gemm_qkv(const bf16_t* __restrict__ A,
                                                const bf16_t* __restrict__ W,
                                                const float* __restrict__ bias,
                                                bf16_t* __restrict__ qq,
                                                bf16_t* __restrict__ kpb,
                                                bf16_t* __restrict__ vtb) {
  __shared__ __align__(16) bf16_t As[128 * 64];
  __shared__ __align__(16) bf16_t Bs[128 * 64];
  const int K = 1024;
  const int tid = threadIdx.x;
  const int w = tid >> 6, lane = tid & 63;
  const int m16 = lane & 15, quad = lane >> 4;
  const int wm = w & 1, wn = w >> 1;
  const int n0 = blockIdx.x * 128, m0 = blockIdx.y * 128;

  f32x4 acc[4][4];
#pragma unroll
  for (int i = 0; i < 4; ++i)
#pragma unroll
    for (int j = 0; j < 4; ++j) acc[i][j] = (f32x4){0.f, 0.f, 0.f, 0.f};

  int rowi[4], gci[4];
#pragma unroll
  for (int i = 0; i < 4; ++i) {
    int p = (w * 4 + i) * 64 + lane;
    rowi[i] = p >> 3;
    gci[i] = ((lane & 7) ^ (rowi[i] & 7)) * 8;
  }

  for (int kt = 0; kt < K; kt += 64) {
    __syncthreads();
#pragma unroll
    for (int i = 0; i < 4; ++i) {
      async_load16(A + (size_t)(m0 + rowi[i]) * K + kt + gci[i], &As[(w * 4 + i) * 512]);
      async_load16(W + (size_t)(n0 + rowi[i]) * K + kt + gci[i], &Bs[(w * 4 + i) * 512]);
    }
    __syncthreads();
#pragma unroll
    for (int kk = 0; kk < 2; ++kk) {
      bf16x8 af[4], bfv[4];
#pragma unroll
      for (int mi = 0; mi < 4; ++mi) {
        int row = wm * 64 + mi * 16 + m16;
        int cpos = (kk * 4 + quad) ^ (row & 7);
        af[mi] = *(const bf16x8*)&As[row * 64 + cpos * 8];
      }
#pragma unroll
      for (int ni = 0; ni < 4; ++ni) {
        int row = wn * 64 + ni * 16 + m16;
        int cpos = (kk * 4 + quad) ^ (row & 7);
        bfv[ni] = *(const bf16x8*)&Bs[row * 64 + cpos * 8];
      }
#pragma unroll
      for (int mi = 0; mi < 4; ++mi)
#pragma unroll
        for (int ni = 0; ni < 4; ++ni)
          acc[mi][ni] = __builtin_amdgcn_mfma_f32_16x16x32_bf16(af[mi], bfv[ni],
                                                                acc[mi][ni], 0, 0, 0);
    }
  }

  const int sec = n0 >> 10;  // 0=Q, 1=K, 2=V (block-uniform)
#pragma unroll
  for (int ni = 0; ni < 4; ++ni) {
    int col = n0 + wn * 64 + ni * 16 + m16;
    float bv = bias[col];
    int c2 = col & 1023, hh = c2 >> 6, d = c2 & 63;
#pragma unroll
    for (int mi = 0; mi < 4; ++mi) {
      int rowb = m0 + wm * 64 + mi * 16 + quad * 4;
      int bb = rowb >> 11, t = rowb & 2047;
      float v[4];
#pragma unroll
      for (int r = 0; r < 4; ++r) v[r] = acc[mi][ni][r] + bv;
      if (sec == 0) {
#pragma unroll
        for (int r = 0; r < 4; ++r)
          qq[(size_t)(rowb + r) * 1024 + col] = (bf16_t)v[r];
      } else if (sec == 1) {
        bf16_t* kdst = kpb + (((size_t)(bb * 16 + hh) * 2048 + t) * 64 + d);
#pragma unroll
        for (int r = 0; r < 4; ++r) kdst[r * 64] = (bf16_t)v[r];
      } else {
        U32P a2, c3;
        a2.h[0] = (bf16_t)v[0]; a2.h[1] = (bf16_t)v[1];
        c3.h[0] = (bf16_t)v[2]; c3.h[1] = (bf16_t)v[3];
        uint2 pk; pk.x = a2.u; pk.y = c3.u;
        *(uint2*)(vtb + (((size_t)(bb * 16 + hh) * 64 + d) * 2048 + t)) = pk;
      }
    }
  }
}

// ---- split-K=2 GEMM -> bf16 partial buffers (no bias) ----------------------
__global__ __launch_bounds__(256) void gemm_sk2(const bf16_t* __restrict__ A,
                                                const bf16_t* __restrict__ W,
                                                bf16_t* __restrict__ p0,
                                                bf16_t* __restrict__ p1,
                                                int M, int N, int K) {
  __shared__ __align__(16) bf16_t As[128 * 64];
  __shared__ __align__(16) bf16_t Bs[128 * 64];
  const int tid = threadIdx.x;
  const int w = tid >> 6, lane = tid & 63;
  const int m16 = lane & 15, quad = lane >> 4;
  const int wm = w & 1, wn = w >> 1;
  const int n0 = blockIdx.x * 128, m0 = blockIdx.y * 128;
  const int z = blockIdx.z;
  const int kbeg = z * (K >> 1), kend = kbeg + (K >> 1);
  bf16_t* outb = z ? p1 : p0;

  f32x4 acc[4][4];
#pragma unroll
  for (int i = 0; i < 4; ++i)
#pragma unroll
    for (int j = 0; j < 4; ++j) acc[i][j] = (f32x4){0.f, 0.f, 0.f, 0.f};

  int rowi[4], gci[4];
#pragma unroll
  for (int i = 0; i < 4; ++i) {
    int p = (w * 4 + i) * 64 + lane;
    rowi[i] = p >> 3;
    gci[i] = ((lane & 7) ^ (rowi[i] & 7)) * 8;
  }

  for (int kt = kbeg; kt < kend; kt += 64) {
    __syncthreads();
#pragma unroll
    for (int i = 0; i < 4; ++i) {
      async_load16(A + (size_t)(m0 + rowi[i]) * K + kt + gci[i], &As[(w * 4 + i) * 512]);
      async_load16(W + (size_t)(n0 + rowi[i]) * K + kt + gci[i], &Bs[(w * 4 + i) * 512]);
    }
    __syncthreads();
#pragma unroll
    for (int kk = 0; kk < 2; ++kk) {
      bf16x8 af[4], bfv[4];
#pragma unroll
      for (int mi = 0; mi < 4; ++mi) {
        int row = wm * 64 + mi * 16 + m16;
        int cpos = (kk * 4 + quad) ^ (row & 7);
        af[mi] = *(const bf16x8*)&As[row * 64 + cpos * 8];
      }
#pragma unroll
      for (int ni = 0; ni < 4; ++ni) {
        int row = wn * 64 + ni * 16 + m16;
        int cpos = (kk * 4 + quad) ^ (row & 7);
        bfv[ni] = *(const bf16x8*)&Bs[row * 64 + cpos * 8];
      }
#pragma unroll
      for (int mi = 0; mi < 4; ++mi)
#pragma unroll
        for (int ni = 0; ni < 4; ++ni)
          acc[mi][ni] = __builtin_amdgcn_mfma_f32_16x16x32_bf16(af[mi], bfv[ni],
                                                                acc[mi][ni], 0, 0, 0);
    }
  }

#pragma unroll
  for (int ni = 0; ni < 4; ++ni) {
    int col = n0 + wn * 64 + ni * 16 + m16;
#pragma unroll
    for (int mi = 0; mi < 4; ++mi) {
      int rowb = m0 + wm * 64 + mi * 16 + quad * 4;
#pragma unroll
      for (int r = 0; r < 4; ++r) {
        size_t idx = (size_t)(rowb + r) * N + col;
        outb[idx] = (bf16_t)acc[mi][ni][r];
      }
    }
  }
}

// ---------------- Flash attention v7: per-wave, uniform k-chunks + partials -
// Wave = (bh, 16-q strip, 768-key slot): max 24 iterations -> balanced grid
// with ~3x oversubscription so co-resident waves hide the per-iter latency
// chain (r6 failure mode: tail waves ran solo at ~2.3us/iter). Stateless
// log2-softmax (analytic max) makes key-subsets associative. P stays in
// registers (S-output == PV B-frag via interleaved key rows). K and V both
// register-prefetched one iteration ahead. Partials: O (bf16, un-normalized)
// + l per slot; combine kernel recomputes slot validity bit-identically.
__global__ __launch_bounds__(256, 4) void attn_part(const bf16_t* __restrict__ qq,
                                                    const bf16_t* __restrict__ kp,
                                                    const bf16_t* __restrict__ vT,
                                                    bf16_t* __restrict__ P,
                                                    float* __restrict__ lbuf) {
  const int u = blockIdx.x * 4 + (threadIdx.x >> 6);  // 0..12287
  const int bh = u & 31;
  const int w2 = u >> 5;            // 0..383
  const int slot = w2 % 3;
  const int q16 = 127 - w2 / 3;     // heavy strips first
  const int b = bh >> 4, h = bh & 15;
  const int lane = threadIdx.x & 63;
  const int m16 = lane & 15, quad = lane >> 4;
  const int q_lo = q16 << 4, q_hi = q_lo + 15;

  const float slope2 = __builtin_amdgcn_exp2f(-0.5f * (float)(h + 1))
                       * 1.4426950408889634f;  // slope_h * log2(e)
  const int win = (int)(30.0f / slope2);
  int ks = q_lo - win; if (ks < 0) ks = 0; ks &= ~31;
  const int s_lo = (ks > slot * 768) ? ks : slot * 768;
  const int s_hi_raw = slot * 768 + 767;
  const int s_hi = (q_hi < s_hi_raw) ? q_hi : s_hi_raw;
  if (s_lo > s_hi) return;

  // Q B-fragments (n=q, k=d)
  const bf16_t* qb = qq + (size_t)(b * SS + q_lo + m16) * 1024 + h * 64 + quad * 8;
  const bf16x8 bq0 = *(const bf16x8*)(qb);
  const bf16x8 bq1 = *(const bf16x8*)(qb + 32);

  // interleaved key-row map so S output regs == PV B-frag
  const int rX = ((m16 >> 2) << 3) + (m16 & 3);
  const bf16_t* kb0 = kp + ((size_t)bh * 2048 + rX) * 64 + quad * 8;
  const bf16_t* vb0 = vT + ((size_t)bh * 64 + m16) * 2048 + quad * 8;

  const float d32 = slope2 * 32.0f;
  float alkX[4], alkY[4];
#pragma unroll
  for (int r = 0; r < 4; ++r) {
    alkX[r] = slope2 * (float)(s_lo + quad * 8 + r - q_lo - m16);
    alkY[r] = alkX[r] + slope2 * 4.0f;
  }

  f32x4 acc[4];
#pragma unroll
  for (int i = 0; i < 4; ++i) acc[i] = (f32x4){0.f, 0.f, 0.f, 0.f};
  float rs = 0.f;
  constexpr float C = 0.18033688011112042f;  // log2(e)/8

  // preload first iteration K and V
  bf16x8 aX0, aX1, aY0, aY1, av0, av1, av2, av3;
  {
    const bf16_t* kx = kb0 + (size_t)s_lo * 64;
    aX0 = *(const bf16x8*)(kx);
    aX1 = *(const bf16x8*)(kx + 32);
    aY0 = *(const bf16x8*)(kx + 256);
    aY1 = *(const bf16x8*)(kx + 288);
    const bf16_t* vx = vb0 + s_lo;
    av0 = *(const bf16x8*)(vx);
    av1 = *(const bf16x8*)(vx + 16 * 2048);
    av2 = *(const bf16x8*)(vx + 32 * 2048);
    av3 = *(const bf16x8*)(vx + 48 * 2048);
  }

  for (int kb = s_lo; kb <= s_hi; kb += 32) {
    bf16x8 nX0 = aX0, nX1 = aX1, nY0 = aY0, nY1 = aY1;
    bf16x8 nv0 = av0, nv1 = av1, nv2 = av2, nv3 = av3;
    if (kb + 32 <= s_hi) {  // prefetch next iteration K and V
      const bf16_t* kx = kb0 + (size_t)(kb + 32) * 64;
      nX0 = *(const bf16x8*)(kx);
      nX1 = *(const bf16x8*)(kx + 32);
      nY0 = *(const bf16x8*)(kx + 256);
      nY1 = *(const bf16x8*)(kx + 288);
      const bf16_t* vx = vb0 + (kb + 32);
      nv0 = *(const bf16x8*)(vx);
      nv1 = *(const bf16x8*)(vx + 16 * 2048);
      nv2 = *(const bf16x8*)(vx + 32 * 2048);
      nv3 = *(const bf16x8*)(vx + 48 * 2048);
    }

    f32x4 zX = (f32x4){0.f, 0.f, 0.f, 0.f};
    zX = __builtin_amdgcn_mfma_f32_16x16x32_bf16(aX0, bq0, zX, 0, 0, 0);
    zX = __builtin_amdgcn_mfma_f32_16x16x32_bf16(aX1, bq1, zX, 0, 0, 0);
    f32x4 zY = (f32x4){0.f, 0.f, 0.f, 0.f};
    zY = __builtin_amdgcn_mfma_f32_16x16x32_bf16(aY0, bq0, zY, 0, 0, 0);
    zY = __builtin_amdgcn_mfma_f32_16x16x32_bf16(aY1, bq1, zY, 0, 0, 0);

    bf16x8 bp;
#pragma unroll
    for (int r = 0; r < 4; ++r) {
      float sX = fmaf(zX[r], C, alkX[r]);
      float sY = fmaf(zY[r], C, alkY[r]);
      float eX = (alkX[r] > 0.0f) ? 0.0f : __builtin_amdgcn_exp2f(sX);  // causal
      float eY = (alkY[r] > 0.0f) ? 0.0f : __builtin_amdgcn_exp2f(sY);
      bp[r] = (bf16_t)eX;
      bp[4 + r] = (bf16_t)eY;
      rs += eX + eY;
      alkX[r] += d32;
      alkY[r] += d32;
    }

    acc[0] = __builtin_amdgcn_mfma_f32_16x16x32_bf16(av0, bp, acc[0], 0, 0, 0);
    acc[1] = __builtin_amdgcn_mfma_f32_16x16x32_bf16(av1, bp, acc[1], 0, 0, 0);
    acc[2] = __builtin_amdgcn_mfma_f32_16x16x32_bf16(av2, bp, acc[2], 0, 0, 0);
    acc[3] = __builtin_amdgcn_mfma_f32_16x16x32_bf16(av3, bp, acc[3], 0, 0, 0);

    aX0 = nX0; aX1 = nX1; aY0 = nY0; aY1 = nY1;
    av0 = nv0; av1 = nv1; av2 = nv2; av3 = nv3;
  }

  // epilogue: un-normalized O partial [q(16)][d(64)] bf16 + per-q l
  rs += __shfl_xor(rs, 16);
  rs += __shfl_xor(rs, 32);
  const size_t base = ((size_t)(bh * 3 + slot) * 128 + q16);
  bf16_t* ob = P + base * 1024 + (size_t)m16 * 64 + quad * 4;
#pragma unroll
  for (int s = 0; s < 4; ++s) {
    U32P a2, c2;
    a2.h[0] = (bf16_t)acc[s][0]; a2.h[1] = (bf16_t)acc[s][1];
    c2.h[0] = (bf16_t)acc[s][2]; c2.h[1] = (bf16_t)acc[s][3];
    uint2 pk; pk.x = a2.u; pk.y = c2.u;
    *(uint2*)(ob + s * 16) = pk;
  }
  if (quad == 0) lbuf[base * 16 + m16] = rs;
}

// ---- combine: ctx[q][d] = sum_valid_slots O_s / sum l_s --------------------
__global__ __launch_bounds__(256) void attn_comb(const bf16_t* __restrict__ P,
                                                 const float* __restrict__ lbuf,
                                                 bf16_t* __restrict__ ctx) {
  const int gi = blockIdx.x * 4 + (threadIdx.x >> 6);  // strip id 0..4095
  const int bh = gi & 31, q16 = gi >> 5;
  const int b = bh >> 4, h = bh & 15;
  const int lane = threadIdx.x & 63;
  const int q = lane >> 2, d0 = (lane & 3) * 16;
  const int q_lo = q16 << 4, q_hi = q_lo + 15;

  const float slope2 = __builtin_amdgcn_exp2f(-0.5f * (float)(h + 1))
                       * 1.4426950408889634f;
  const int win = (int)(30.0f / slope2);
  int ks = q_lo - win; if (ks < 0) ks = 0; ks &= ~31;

  float o[16];
#pragma unroll
  for (int i = 0; i < 16; ++i) o[i] = 0.f;
  float lt = 0.f;
#pragma unroll
  for (int slot = 0; slot < 3; ++slot) {
    if (slot * 768 > q_hi) break;
    const int s_lo = (ks > slot * 768) ? ks : slot * 768;
    const int s_hi_raw = slot * 768 + 767;
    const int s_hi = (q_hi < s_hi_raw) ? q_hi : s_hi_raw;
    if (s_lo > s_hi) continue;
    const size_t base = ((size_t)(bh * 3 + slot) * 128 + q16);
    lt += lbuf[base * 16 + q];
    const bf16_t* pb = P + base * 1024 + (size_t)q * 64 + d0;
    bf16x8 x0 = *(const bf16x8*)(pb);
    bf16x8 x1 = *(const bf16x8*)(pb + 8);
#pragma unroll
    for (int i = 0; i < 8; ++i) { o[i] += (float)x0[i]; o[8 + i] += (float)x1[i]; }
  }
  const float inv = 1.0f / lt;
  bf16x8 o0, o1;
#pragma unroll
  for (int i = 0; i < 8; ++i) {
    o0[i] = (bf16_t)(o[i] * inv);
    o1[i] = (bf16_t)(o[8 + i] * inv);
  }
  bf16_t* ob = ctx + (size_t)(b * SS + q_lo + q) * 1024 + h * 64 + d0;
  *(bf16x8*)ob = o0;
  *(bf16x8*)(ob + 8) = o1;
}

// ---------------------------------------------------------------------------
extern "C" void kernel_launch(void* const* d_in, const int* in_sizes, int n_in,
                              void* d_out, int out_size, void* d_ws, size_t ws_size,
                              hipStream_t stream) {
  const float* hs    = (const float*)d_in[0];
  const float* qkvw  = (const float*)d_in[2];
  const float* qkvb  = (const float*)d_in[3];
  const float* dw    = (const float*)d_in[4];
  const float* db    = (const float*)d_in[5];
  const float* w1    = (const float*)d_in[6];
  const float* b1    = (const float*)d_in[7];
  const float* w2    = (const float*)d_in[8];
  const float* b2    = (const float*)d_in[9];
  const float* ln1w  = (const float*)d_in[10];
  const float* ln1b  = (const float*)d_in[11];
  const float* ln2w  = (const float*)d_in[12];
  const float* ln2b  = (const float*)d_in[13];
  float* x = (float*)d_out;  // residual stream, fp32 [4096,1024]

  char* ws = (char*)d_ws;
  bf16_t* wq  = (bf16_t*)(ws + 0);         // 6 MB
  bf16_t* wd  = (bf16_t*)(ws + 6291456);   // 2 MB
  bf16_t* w1c = (bf16_t*)(ws + 8388608);   // 8 MB
  bf16_t* w2c = (bf16_t*)(ws + 16777216);  // 8 MB
  bf16_t* hb  = (bf16_t*)(ws + 25165824);  // 8 MB (ln out / mlp2 partial0)
  bf16_t* qq  = (bf16_t*)(ws + 33554432);  // 8 MB Q rows
  bf16_t* kpb = (bf16_t*)(ws + 41943040);  // 8 MB K packed [bh][t][d]
  bf16_t* vtb = (bf16_t*)(ws + 50331648);  // 8 MB V transposed [bh][d][t]
  bf16_t* cx  = (bf16_t*)(ws + 58720256);  // 8 MB attn ctx
  bf16_t* Pp  = (bf16_t*)(ws + 67108864);  // 25.2 MB attn O-partials [bh][slot][strip]
  float*  lb  = (float*)(ws + 92274688);   // 0.79 MB l partials
  bf16_t* qmid = (bf16_t*)(ws + 33554432); // 32 MB mlp-mid (qq/kp/vT/cx dead)
  bf16_t* p2b = (bf16_t*)(ws + 67108864);  // 8 MB mlp2 partial1 (P dead post-comb)
  bf16_t* dp0 = qq;                        // dense partials (qq/kp dead post-attn)
  bf16_t* dp1 = kpb;

  hipMemcpyAsync(x, hs, (size_t)4096 * 1024 * 4, hipMemcpyDeviceToDevice, stream);

  for (int l = 0; l < 2; ++l) {
    cvt_kernel<<<3072, 256, 0, stream>>>(qkvw + (size_t)l * 3145728, wq);
    cvt_kernel<<<1024, 256, 0, stream>>>(dw + (size_t)l * 1048576, wd);
    cvt_kernel<<<4096, 256, 0, stream>>>(w1 + (size_t)l * 4194304, w1c);
    cvt_kernel<<<4096, 256, 0, stream>>>(w2 + (size_t)l * 4194304, w2c);

    ln_kernel<<<4096, 256, 0, stream>>>(x, ln1w + l * 1024, ln1b + l * 1024, hb);
    gemm_qkv<<<dim3(24, 32), 256, 0, stream>>>(hb, wq, qkvb + l * 3072, qq, kpb, vtb);
    attn_part<<<3072, 256, 0, stream>>>(qq, kpb, vtb, Pp, lb);
    attn_comb<<<1024, 256, 0, stream>>>(Pp, lb, cx);
    gemm_sk2<<<dim3(8, 32, 2), 256, 0, stream>>>(cx, wd, dp0, dp1, 4096, 1024, 1024);
    fuse_add<<<4096, 256, 0, stream>>>(x, dp0, dp1, db + l * 1024);
    ln_kernel<<<4096, 256, 0, stream>>>(x, ln2w + l * 1024, ln2b + l * 1024, hb);
    gemm_bt<1><<<dim3(32, 32), 256, 0, stream>>>(hb, w1c, b1 + l * 4096, qmid,
                                                 4096, 4096, 1024);
    gemm_sk2<<<dim3(8, 32, 2), 256, 0, stream>>>(qmid, w2c, hb, p2b, 4096, 1024, 4096);
    fuse_add<<<4096, 256, 0, stream>>>(x, hb, p2b, b2 + l * 1024);
  }
}

// Round 8
// 764.549 us; speedup vs baseline: 1.1037x; 1.1030x over previous
//
#include <hip/hip_runtime.h>
#include <cstdint>
#include <cmath>

#define SS 2048
#define HH 1024
#define QPAD 1040   // qq row stride (pad breaks 2 KB power-of-2 channel aliasing)
#define VPAD 2080   // vT row stride (pad breaks 4 KB power-of-2 channel aliasing)

typedef __bf16 bf16_t;
typedef __bf16 bf16x8 __attribute__((ext_vector_type(8)));
typedef __bf16 bf16x4 __attribute__((ext_vector_type(4)));
typedef float  f32x4  __attribute__((ext_vector_type(4)));

union U32P { unsigned u; bf16_t h[2]; };

__device__ __forceinline__ void async_load16(const void* g, void* l) {
  __builtin_amdgcn_global_load_lds(
      (__attribute__((address_space(1))) void*)(g),
      (__attribute__((address_space(3))) void*)(l), 16, 0, 0);
}

// ---------------- fp32 -> bf16 convert ------------------------------------
__global__ __launch_bounds__(256) void cvt_kernel(const float* __restrict__ in,
                                                  bf16_t* __restrict__ out) {
  size_t i = (size_t)blockIdx.x * 256 + threadIdx.x;
  f32x4 v = ((const f32x4*)in)[i];
  bf16x4 o;
  o[0] = (bf16_t)v[0]; o[1] = (bf16_t)v[1]; o[2] = (bf16_t)v[2]; o[3] = (bf16_t)v[3];
  ((bf16x4*)out)[i] = o;
}

// ---------------- LayerNorm: fp32 in [4096,1024] -> bf16 out ---------------
__global__ __launch_bounds__(256) void ln_kernel(const float* __restrict__ x,
                                                 const float* __restrict__ w,
                                                 const float* __restrict__ b,
                                                 bf16_t* __restrict__ out) {
  const int row = blockIdx.x;
  const int tid = threadIdx.x;
  const f32x4 v = ((const f32x4*)(x + (size_t)row * HH))[tid];
  float s  = v[0] + v[1] + v[2] + v[3];
  float s2 = v[0]*v[0] + v[1]*v[1] + v[2]*v[2] + v[3]*v[3];
#pragma unroll
  for (int o = 1; o < 64; o <<= 1) { s += __shfl_xor(s, o); s2 += __shfl_xor(s2, o); }
  __shared__ float r1[4], r2[4];
  if ((tid & 63) == 0) { r1[tid >> 6] = s; r2[tid >> 6] = s2; }
  __syncthreads();
  float ts  = r1[0] + r1[1] + r1[2] + r1[3];
  float ts2 = r2[0] + r2[1] + r2[2] + r2[3];
  float mu  = ts * (1.0f / HH);
  float var = ts2 * (1.0f / HH) - mu * mu;
  float rstd = rsqrtf(var + 1e-5f);
  f32x4 wv = ((const f32x4*)w)[tid];
  f32x4 bv = ((const f32x4*)b)[tid];
  bf16x4 o;
#pragma unroll
  for (int j = 0; j < 4; ++j) o[j] = (bf16_t)((v[j] - mu) * rstd * wv[j] + bv[j]);
  ((bf16x4*)(out + (size_t)row * HH))[tid] = o;
}

__device__ __forceinline__ float gelu_f(float x) {
  return 0.5f * x * (1.0f + erff(x * 0.70710678118654752f));
}

// ---- fused residual add: x += p0 + p1 + bias -------------------------------
__global__ __launch_bounds__(256) void fuse_add(float* __restrict__ x,
                                                const bf16_t* __restrict__ p0,
                                                const bf16_t* __restrict__ p1,
                                                const float* __restrict__ bias) {
  size_t i = (size_t)blockIdx.x * 256 + threadIdx.x;
  f32x4 xv = ((f32x4*)x)[i];
  bf16x4 a = ((const bf16x4*)p0)[i];
  bf16x4 b4 = ((const bf16x4*)p1)[i];
  f32x4 bv = ((const f32x4*)bias)[i & 255];
#pragma unroll
  for (int j = 0; j < 4; ++j) xv[j] += (float)a[j] + (float)b4[j] + bv[j];
  ((f32x4*)x)[i] = xv;
}

// ---------------- GEMM: C = A * W^T + bias; EPI 1=bias+gelu -----------------
template <int EPI>
__global__ __launch_bounds__(256) void gemm_bt(const bf16_t* __restrict__ A,
                                               const bf16_t* __restrict__ W,
                                               const float* __restrict__ bias,
                                               bf16_t* __restrict__ outb,
                                               int M, int N, int K) {
  __shared__ __align__(16) bf16_t As[128 * 64];
  __shared__ __align__(16) bf16_t Bs[128 * 64];
  const int tid = threadIdx.x;
  const int w = tid >> 6, lane = tid & 63;
  const int m16 = lane & 15, quad = lane >> 4;
  const int wm = w & 1, wn = w >> 1;
  const int n0 = blockIdx.x * 128, m0 = blockIdx.y * 128;

  f32x4 acc[4][4];
#pragma unroll
  for (int i = 0; i < 4; ++i)
#pragma unroll
    for (int j = 0; j < 4; ++j) acc[i][j] = (f32x4){0.f, 0.f, 0.f, 0.f};

  int rowi[4], gci[4];
#pragma unroll
  for (int i = 0; i < 4; ++i) {
    int p = (w * 4 + i) * 64 + lane;
    rowi[i] = p >> 3;
    gci[i] = ((lane & 7) ^ (rowi[i] & 7)) * 8;
  }

  for (int kt = 0; kt < K; kt += 64) {
    __syncthreads();
#pragma unroll
    for (int i = 0; i < 4; ++i) {
      async_load16(A + (size_t)(m0 + rowi[i]) * K + kt + gci[i], &As[(w * 4 + i) * 512]);
      async_load16(W + (size_t)(n0 + rowi[i]) * K + kt + gci[i], &Bs[(w * 4 + i) * 512]);
    }
    __syncthreads();
#pragma unroll
    for (int kk = 0; kk < 2; ++kk) {
      bf16x8 af[4], bfv[4];
#pragma unroll
      for (int mi = 0; mi < 4; ++mi) {
        int row = wm * 64 + mi * 16 + m16;
        int cpos = (kk * 4 + quad) ^ (row & 7);
        af[mi] = *(const bf16x8*)&As[row * 64 + cpos * 8];
      }
#pragma unroll
      for (int ni = 0; ni < 4; ++ni) {
        int row = wn * 64 + ni * 16 + m16;
        int cpos = (kk * 4 + quad) ^ (row & 7);
        bfv[ni] = *(const bf16x8*)&Bs[row * 64 + cpos * 8];
      }
#pragma unroll
      for (int mi = 0; mi < 4; ++mi)
#pragma unroll
        for (int ni = 0; ni < 4; ++ni)
          acc[mi][ni] = __builtin_amdgcn_mfma_f32_16x16x32_bf16(af[mi], bfv[ni],
                                                                acc[mi][ni], 0, 0, 0);
    }
  }

#pragma unroll
  for (int ni = 0; ni < 4; ++ni) {
    int col = n0 + wn * 64 + ni * 16 + m16;
    float bv = bias[col];
#pragma unroll
    for (int mi = 0; mi < 4; ++mi) {
      int rowb = m0 + wm * 64 + mi * 16 + quad * 4;
#pragma unroll
      for (int r = 0; r < 4; ++r) {
        size_t idx = (size_t)(rowb + r) * N + col;
        float v = acc[mi][ni][r] + bv;
        if constexpr (EPI == 1) v = gelu_f(v);
        outb[idx] = (bf16_t)v;
      }
    }
  }
}

// ---- QKV GEMM: Q -> qq (row stride QPAD); K -> kp[bh][t][d];
// ---- V -> vT[bh][d][t] with row stride VPAD (anti-channel-conflict pad) ----
__global__ __launch_bounds__(256) void gemm_qkv(const bf16_t* __restrict__ A,
                                                const bf16_t* __restrict__ W,
                                                const float* __restrict__ bias,
                                                bf16_t* __restrict__ qq,
                                                bf16_t* __restrict__ kpb,
                                                bf16_t* __restrict__ vtb) {
  __shared__ __align__(16) bf16_t As[128 * 64];
  __shared__ __align__(16) bf16_t Bs[128 * 64];
  const int K = 1024;
  const int tid = threadIdx.x;
  const int w = tid >> 6, lane = tid & 63;
  const int m16 = lane & 15, quad = lane >> 4;
  const int wm = w & 1, wn = w >> 1;
  const int n0 = blockIdx.x * 128, m0 = blockIdx.y * 128;

  f32x4 acc[4][4];
#pragma unroll
  for (int i = 0; i < 4; ++i)
#pragma unroll
    for (int j = 0; j < 4; ++j) acc[i][j] = (f32x4){0.f, 0.f, 0.f, 0.f};

  int rowi[4], gci[4];
#pragma unroll
  for (int i = 0; i < 4; ++i) {
    int p = (w * 4 + i) * 64 + lane;
    rowi[i] = p >> 3;
    gci[i] = ((lane & 7) ^ (rowi[i] & 7)) * 8;
  }

  for (int kt = 0; kt < K; kt += 64) {
    __syncthreads();
#pragma unroll
    for (int i = 0; i < 4; ++i) {
      async_load16(A + (size_t)(m0 + rowi[i]) * K + kt + gci[i], &As[(w * 4 + i) * 512]);
      async_load16(W + (size_t)(n0 + rowi[i]) * K + kt + gci[i], &Bs[(w * 4 + i) * 512]);
    }
    __syncthreads();
#pragma unroll
    for (int kk = 0; kk < 2; ++kk) {
      bf16x8 af[4], bfv[4];
#pragma unroll
      for (int mi = 0; mi < 4; ++mi) {
        int row = wm * 64 + mi * 16 + m16;
        int cpos = (kk * 4 + quad) ^ (row & 7);
        af[mi] = *(const bf16x8*)&As[row * 64 + cpos * 8];
      }
#pragma unroll
      for (int ni = 0; ni < 4; ++ni) {
        int row = wn * 64 + ni * 16 + m16;
        int cpos = (kk * 4 + quad) ^ (row & 7);
        bfv[ni] = *(const bf16x8*)&Bs[row * 64 + cpos * 8];
      }
#pragma unroll
      for (int mi = 0; mi < 4; ++mi)
#pragma unroll
        for (int ni = 0; ni < 4; ++ni)
          acc[mi][ni] = __builtin_amdgcn_mfma_f32_16x16x32_bf16(af[mi], bfv[ni],
                                                                acc[mi][ni], 0, 0, 0);
    }
  }

  const int sec = n0 >> 10;  // 0=Q, 1=K, 2=V (block-uniform)
#pragma unroll
  for (int ni = 0; ni < 4; ++ni) {
    int col = n0 + wn * 64 + ni * 16 + m16;
    float bv = bias[col];
    int c2 = col & 1023, hh = c2 >> 6, d = c2 & 63;
#pragma unroll
    for (int mi = 0; mi < 4; ++mi) {
      int rowb = m0 + wm * 64 + mi * 16 + quad * 4;
      int bb = rowb >> 11, t = rowb & 2047;
      float v[4];
#pragma unroll
      for (int r = 0; r < 4; ++r) v[r] = acc[mi][ni][r] + bv;
      if (sec == 0) {
#pragma unroll
        for (int r = 0; r < 4; ++r)
          qq[(size_t)(rowb + r) * QPAD + col] = (bf16_t)v[r];
      } else if (sec == 1) {
        bf16_t* kdst = kpb + (((size_t)(bb * 16 + hh) * 2048 + t) * 64 + d);
#pragma unroll
        for (int r = 0; r < 4; ++r) kdst[r * 64] = (bf16_t)v[r];
      } else {
        U32P a2, c3;
        a2.h[0] = (bf16_t)v[0]; a2.h[1] = (bf16_t)v[1];
        c3.h[0] = (bf16_t)v[2]; c3.h[1] = (bf16_t)v[3];
        uint2 pk; pk.x = a2.u; pk.y = c3.u;
        *(uint2*)(vtb + (((size_t)(bb * 16 + hh) * 64 + d) * VPAD + t)) = pk;
      }
    }
  }
}

// ---- split-K=2 GEMM -> bf16 partial buffers (no bias) ----------------------
__global__ __launch_bounds__(256) void gemm_sk2(const bf16_t* __restrict__ A,
                                                const bf16_t* __restrict__ W,
                                                bf16_t* __restrict__ p0,
                                                bf16_t* __restrict__ p1,
                                                int M, int N, int K) {
  __shared__ __align__(16) bf16_t As[128 * 64];
  __shared__ __align__(16) bf16_t Bs[128 * 64];
  const int tid = threadIdx.x;
  const int w = tid >> 6, lane = tid & 63;
  const int m16 = lane & 15, quad = lane >> 4;
  const int wm = w & 1, wn = w >> 1;
  const int n0 = blockIdx.x * 128, m0 = blockIdx.y * 128;
  const int z = blockIdx.z;
  const int kbeg = z * (K >> 1), kend = kbeg + (K >> 1);
  bf16_t* outb = z ? p1 : p0;

  f32x4 acc[4][4];
#pragma unroll
  for (int i = 0; i < 4; ++i)
#pragma unroll
    for (int j = 0; j < 4; ++j) acc[i][j] = (f32x4){0.f, 0.f, 0.f, 0.f};

  int rowi[4], gci[4];
#pragma unroll
  for (int i = 0; i < 4; ++i) {
    int p = (w * 4 + i) * 64 + lane;
    rowi[i] = p >> 3;
    gci[i] = ((lane & 7) ^ (rowi[i] & 7)) * 8;
  }

  for (int kt = kbeg; kt < kend; kt += 64) {
    __syncthreads();
#pragma unroll
    for (int i = 0; i < 4; ++i) {
      async_load16(A + (size_t)(m0 + rowi[i]) * K + kt + gci[i], &As[(w * 4 + i) * 512]);
      async_load16(W + (size_t)(n0 + rowi[i]) * K + kt + gci[i], &Bs[(w * 4 + i) * 512]);
    }
    __syncthreads();
#pragma unroll
    for (int kk = 0; kk < 2; ++kk) {
      bf16x8 af[4], bfv[4];
#pragma unroll
      for (int mi = 0; mi < 4; ++mi) {
        int row = wm * 64 + mi * 16 + m16;
        int cpos = (kk * 4 + quad) ^ (row & 7);
        af[mi] = *(const bf16x8*)&As[row * 64 + cpos * 8];
      }
#pragma unroll
      for (int ni = 0; ni < 4; ++ni) {
        int row = wn * 64 + ni * 16 + m16;
        int cpos = (kk * 4 + quad) ^ (row & 7);
        bfv[ni] = *(const bf16x8*)&Bs[row * 64 + cpos * 8];
      }
#pragma unroll
      for (int mi = 0; mi < 4; ++mi)
#pragma unroll
        for (int ni = 0; ni < 4; ++ni)
          acc[mi][ni] = __builtin_amdgcn_mfma_f32_16x16x32_bf16(af[mi], bfv[ni],
                                                                acc[mi][ni], 0, 0, 0);
    }
  }

#pragma unroll
  for (int ni = 0; ni < 4; ++ni) {
    int col = n0 + wn * 64 + ni * 16 + m16;
#pragma unroll
    for (int mi = 0; mi < 4; ++mi) {
      int rowb = m0 + wm * 64 + mi * 16 + quad * 4;
#pragma unroll
      for (int r = 0; r < 4; ++r) {
        size_t idx = (size_t)(rowb + r) * N + col;
        outb[idx] = (bf16_t)acc[mi][ni][r];
      }
    }
  }
}

// ---------------- Flash attention v8: v7 + anti-channel-conflict padding ----
// IDENTICAL structure to v7 (per-wave uniform k-chunks, stateless softmax,
// all-register P, K+V prefetch). Single change: vT/qq row strides padded off
// powers of 2 (4160 B / 2080 B) so the 16-row strided MFMA A-operand loads
// spread across memory channels instead of serializing on one.
__global__ __launch_bounds__(256, 4) void attn_part(const bf16_t* __restrict__ qq,
                                                    const bf16_t* __restrict__ kp,
                                                    const bf16_t* __restrict__ vT,
                                                    bf16_t* __restrict__ P,
                                                    float* __restrict__ lbuf) {
  const int u = blockIdx.x * 4 + (threadIdx.x >> 6);  // 0..12287
  const int bh = u & 31;
  const int w2 = u >> 5;            // 0..383
  const int slot = w2 % 3;
  const int q16 = 127 - w2 / 3;     // heavy strips first
  const int b = bh >> 4, h = bh & 15;
  const int lane = threadIdx.x & 63;
  const int m16 = lane & 15, quad = lane >> 4;
  const int q_lo = q16 << 4, q_hi = q_lo + 15;

  const float slope2 = __builtin_amdgcn_exp2f(-0.5f * (float)(h + 1))
                       * 1.4426950408889634f;  // slope_h * log2(e)
  const int win = (int)(30.0f / slope2);
  int ks = q_lo - win; if (ks < 0) ks = 0; ks &= ~31;
  const int s_lo = (ks > slot * 768) ? ks : slot * 768;
  const int s_hi_raw = slot * 768 + 767;
  const int s_hi = (q_hi < s_hi_raw) ? q_hi : s_hi_raw;
  if (s_lo > s_hi) return;

  // Q B-fragments (n=q, k=d)
  const bf16_t* qb = qq + (size_t)(b * SS + q_lo + m16) * QPAD + h * 64 + quad * 8;
  const bf16x8 bq0 = *(const bf16x8*)(qb);
  const bf16x8 bq1 = *(const bf16x8*)(qb + 32);

  // interleaved key-row map so S output regs == PV B-frag
  const int rX = ((m16 >> 2) << 3) + (m16 & 3);
  const bf16_t* kb0 = kp + ((size_t)bh * 2048 + rX) * 64 + quad * 8;
  const bf16_t* vb0 = vT + ((size_t)bh * 64 + m16) * VPAD + quad * 8;

  const float d32 = slope2 * 32.0f;
  float alkX[4], alkY[4];
#pragma unroll
  for (int r = 0; r < 4; ++r) {
    alkX[r] = slope2 * (float)(s_lo + quad * 8 + r - q_lo - m16);
    alkY[r] = alkX[r] + slope2 * 4.0f;
  }

  f32x4 acc[4];
#pragma unroll
  for (int i = 0; i < 4; ++i) acc[i] = (f32x4){0.f, 0.f, 0.f, 0.f};
  float rs = 0.f;
  constexpr float C = 0.18033688011112042f;  // log2(e)/8

  // preload first iteration K and V
  bf16x8 aX0, aX1, aY0, aY1, av0, av1, av2, av3;
  {
    const bf16_t* kx = kb0 + (size_t)s_lo * 64;
    aX0 = *(const bf16x8*)(kx);
    aX1 = *(const bf16x8*)(kx + 32);
    aY0 = *(const bf16x8*)(kx + 256);
    aY1 = *(const bf16x8*)(kx + 288);
    const bf16_t* vx = vb0 + s_lo;
    av0 = *(const bf16x8*)(vx);
    av1 = *(const bf16x8*)(vx + 16 * VPAD);
    av2 = *(const bf16x8*)(vx + 32 * VPAD);
    av3 = *(const bf16x8*)(vx + 48 * VPAD);
  }

  for (int kb = s_lo; kb <= s_hi; kb += 32) {
    bf16x8 nX0 = aX0, nX1 = aX1, nY0 = aY0, nY1 = aY1;
    bf16x8 nv0 = av0, nv1 = av1, nv2 = av2, nv3 = av3;
    if (kb + 32 <= s_hi) {  // prefetch next iteration K and V
      const bf16_t* kx = kb0 + (size_t)(kb + 32) * 64;
      nX0 = *(const bf16x8*)(kx);
      nX1 = *(const bf16x8*)(kx + 32);
      nY0 = *(const bf16x8*)(kx + 256);
      nY1 = *(const bf16x8*)(kx + 288);
      const bf16_t* vx = vb0 + (kb + 32);
      nv0 = *(const bf16x8*)(vx);
      nv1 = *(const bf16x8*)(vx + 16 * VPAD);
      nv2 = *(const bf16x8*)(vx + 32 * VPAD);
      nv3 = *(const bf16x8*)(vx + 48 * VPAD);
    }

    f32x4 zX = (f32x4){0.f, 0.f, 0.f, 0.f};
    zX = __builtin_amdgcn_mfma_f32_16x16x32_bf16(aX0, bq0, zX, 0, 0, 0);
    zX = __builtin_amdgcn_mfma_f32_16x16x32_bf16(aX1, bq1, zX, 0, 0, 0);
    f32x4 zY = (f32x4){0.f, 0.f, 0.f, 0.f};
    zY = __builtin_amdgcn_mfma_f32_16x16x32_bf16(aY0, bq0, zY, 0, 0, 0);
    zY = __builtin_amdgcn_mfma_f32_16x16x32_bf16(aY1, bq1, zY, 0, 0, 0);

    bf16x8 bp;
#pragma unroll
    for (int r = 0; r < 4; ++r) {
      float sX = fmaf(zX[r], C, alkX[r]);
      float sY = fmaf(zY[r], C, alkY[r]);
      float eX = (alkX[r] > 0.0f) ? 0.0f : __builtin_amdgcn_exp2f(sX);  // causal
      float eY = (alkY[r] > 0.0f) ? 0.0f : __builtin_amdgcn_exp2f(sY);
      bp[r] = (bf16_t)eX;
      bp[4 + r] = (bf16_t)eY;
      rs += eX + eY;
      alkX[r] += d32;
      alkY[r] += d32;
    }

    acc[0] = __builtin_amdgcn_mfma_f32_16x16x32_bf16(av0, bp, acc[0], 0, 0, 0);
    acc[1] = __builtin_amdgcn_mfma_f32_16x16x32_bf16(av1, bp, acc[1], 0, 0, 0);
    acc[2] = __builtin_amdgcn_mfma_f32_16x16x32_bf16(av2, bp, acc[2], 0, 0, 0);
    acc[3] = __builtin_amdgcn_mfma_f32_16x16x32_bf16(av3, bp, acc[3], 0, 0, 0);

    aX0 = nX0; aX1 = nX1; aY0 = nY0; aY1 = nY1;
    av0 = nv0; av1 = nv1; av2 = nv2; av3 = nv3;
  }

  // epilogue: un-normalized O partial [q(16)][d(64)] bf16 + per-q l
  rs += __shfl_xor(rs, 16);
  rs += __shfl_xor(rs, 32);
  const size_t base = ((size_t)(bh * 3 + slot) * 128 + q16);
  bf16_t* ob = P + base * 1024 + (size_t)m16 * 64 + quad * 4;
#pragma unroll
  for (int s = 0; s < 4; ++s) {
    U32P a2, c2;
    a2.h[0] = (bf16_t)acc[s][0]; a2.h[1] = (bf16_t)acc[s][1];
    c2.h[0] = (bf16_t)acc[s][2]; c2.h[1] = (bf16_t)acc[s][3];
    uint2 pk; pk.x = a2.u; pk.y = c2.u;
    *(uint2*)(ob + s * 16) = pk;
  }
  if (quad == 0) lbuf[base * 16 + m16] = rs;
}

// ---- combine: ctx[q][d] = sum_valid_slots O_s / sum l_s --------------------
__global__ __launch_bounds__(256) void attn_comb(const bf16_t* __restrict__ P,
                                                 const float* __restrict__ lbuf,
                                                 bf16_t* __restrict__ ctx) {
  const int gi = blockIdx.x * 4 + (threadIdx.x >> 6);  // strip id 0..4095
  const int bh = gi & 31, q16 = gi >> 5;
  const int b = bh >> 4, h = bh & 15;
  const int lane = threadIdx.x & 63;
  const int q = lane >> 2, d0 = (lane & 3) * 16;
  const int q_lo = q16 << 4, q_hi = q_lo + 15;

  const float slope2 = __builtin_amdgcn_exp2f(-0.5f * (float)(h + 1))
                       * 1.4426950408889634f;
  const int win = (int)(30.0f / slope2);
  int ks = q_lo - win; if (ks < 0) ks = 0; ks &= ~31;

  float o[16];
#pragma unroll
  for (int i = 0; i < 16; ++i) o[i] = 0.f;
  float lt = 0.f;
#pragma unroll
  for (int slot = 0; slot < 3; ++slot) {
    if (slot * 768 > q_hi) break;
    const int s_lo = (ks > slot * 768) ? ks : slot * 768;
    const int s_hi_raw = slot * 768 + 767;
    const int s_hi = (q_hi < s_hi_raw) ? q_hi : s_hi_raw;
    if (s_lo > s_hi) continue;
    const size_t base = ((size_t)(bh * 3 + slot) * 128 + q16);
    lt += lbuf[base * 16 + q];
    const bf16_t* pb = P + base * 1024 + (size_t)q * 64 + d0;
    bf16x8 x0 = *(const bf16x8*)(pb);
    bf16x8 x1 = *(const bf16x8*)(pb + 8);
#pragma unroll
    for (int i = 0; i < 8; ++i) { o[i] += (float)x0[i]; o[8 + i] += (float)x1[i]; }
  }
  const float inv = 1.0f / lt;
  bf16x8 o0, o1;
#pragma unroll
  for (int i = 0; i < 8; ++i) {
    o0[i] = (bf16_t)(o[i] * inv);
    o1[i] = (bf16_t)(o[8 + i] * inv);
  }
  bf16_t* ob = ctx + (size_t)(b * SS + q_lo + q) * 1024 + h * 64 + d0;
  *(bf16x8*)ob = o0;
  *(bf16x8*)(ob + 8) = o1;
}

// ---------------------------------------------------------------------------
extern "C" void kernel_launch(void* const* d_in, const int* in_sizes, int n_in,
                              void* d_out, int out_size, void* d_ws, size_t ws_size,
                              hipStream_t stream) {
  const float* hs    = (const float*)d_in[0];
  const float* qkvw  = (const float*)d_in[2];
  const float* qkvb  = (const float*)d_in[3];
  const float* dw    = (const float*)d_in[4];
  const float* db    = (const float*)d_in[5];
  const float* w1    = (const float*)d_in[6];
  const float* b1    = (const float*)d_in[7];
  const float* w2    = (const float*)d_in[8];
  const float* b2    = (const float*)d_in[9];
  const float* ln1w  = (const float*)d_in[10];
  const float* ln1b  = (const float*)d_in[11];
  const float* ln2w  = (const float*)d_in[12];
  const float* ln2b  = (const float*)d_in[13];
  float* x = (float*)d_out;  // residual stream, fp32 [4096,1024]

  char* ws = (char*)d_ws;
  bf16_t* wq  = (bf16_t*)(ws + 0);         // 6 MB
  bf16_t* wd  = (bf16_t*)(ws + 6291456);   // 2 MB
  bf16_t* w1c = (bf16_t*)(ws + 8388608);   // 8 MB
  bf16_t* w2c = (bf16_t*)(ws + 16777216);  // 8 MB
  bf16_t* hb  = (bf16_t*)(ws + 25165824);  // 8 MB (ln out / mlp2 partial0)
  bf16_t* qq  = (bf16_t*)(ws + 33554432);  // 8.52 MB Q rows (stride QPAD)
  bf16_t* kpb = (bf16_t*)(ws + 42074112);  // 8 MB K packed [bh][t][d]
  bf16_t* vtb = (bf16_t*)(ws + 50462720);  // 8.52 MB V^T [bh][d][VPAD]
  bf16_t* cx  = (bf16_t*)(ws + 58982400);  // 8 MB attn ctx
  bf16_t* Pp  = (bf16_t*)(ws + 67371008);  // 25.2 MB attn O-partials
  float*  lb  = (float*)(ws + 92536832);   // 0.79 MB l partials
  bf16_t* qmid = (bf16_t*)(ws + 33554432); // 32 MB mlp-mid (qq/kp/vT/cx dead)
  bf16_t* p2b = (bf16_t*)(ws + 67371008);  // 8 MB mlp2 partial1 (P dead post-comb)
  bf16_t* dp0 = qq;                        // dense partials (qq/kp dead post-attn)
  bf16_t* dp1 = kpb;

  hipMemcpyAsync(x, hs, (size_t)4096 * 1024 * 4, hipMemcpyDeviceToDevice, stream);

  for (int l = 0; l < 2; ++l) {
    cvt_kernel<<<3072, 256, 0, stream>>>(qkvw + (size_t)l * 3145728, wq);
    cvt_kernel<<<1024, 256, 0, stream>>>(dw + (size_t)l * 1048576, wd);
    cvt_kernel<<<4096, 256, 0, stream>>>(w1 + (size_t)l * 4194304, w1c);
    cvt_kernel<<<4096, 256, 0, stream>>>(w2 + (size_t)l * 4194304, w2c);

    ln_kernel<<<4096, 256, 0, stream>>>(x, ln1w + l * 1024, ln1b + l * 1024, hb);
    gemm_qkv<<<dim3(24, 32), 256, 0, stream>>>(hb, wq, qkvb + l * 3072, qq, kpb, vtb);
    attn_part<<<3072, 256, 0, stream>>>(qq, kpb, vtb, Pp, lb);
    attn_comb<<<1024, 256, 0, stream>>>(Pp, lb, cx);
    gemm_sk2<<<dim3(8, 32, 2), 256, 0, stream>>>(cx, wd, dp0, dp1, 4096, 1024, 1024);
    fuse_add<<<4096, 256, 0, stream>>>(x, dp0, dp1, db + l * 1024);
    ln_kernel<<<4096, 256, 0, stream>>>(x, ln2w + l * 1024, ln2b + l * 1024, hb);
    gemm_bt<1><<<dim3(32, 32), 256, 0, stream>>>(hb, w1c, b1 + l * 4096, qmid,
                                                 4096, 4096, 1024);
    gemm_sk2<<<dim3(8, 32, 2), 256, 0, stream>>>(qmid, w2c, hb, p2b, 4096, 1024, 4096);
    fuse_add<<<4096, 256, 0, stream>>>(x, hb, p2b, b2 + l * 1024);
  }
}